// Round 12
// baseline (87.394 us; speedup 1.0000x reference)
//
#include <hip/hip_runtime.h>
#include <hip/hip_bf16.h>

// Problem constants
#define Bn 8
#define Tn 2048
#define En 512
#define Hn 16
#define Dn 32
#define NC 32          // scan chunks
#define CL 64          // chunk length (Tn/NC)
#define NT (Bn*Tn)     // 16384 tokens
#define INV_DECAY (1.0f/1.2f)
#define LOG2_INVD (-0.26303440583379383f)   // log2(1/1.2)

typedef __attribute__((ext_vector_type(8))) short  bf16x8;  // 8 bf16 (4 VGPRs)
typedef __attribute__((ext_vector_type(4))) float  f32x4;
typedef __attribute__((ext_vector_type(8))) unsigned short u16x8;

__device__ __forceinline__ unsigned short f2b(float f) {
    __hip_bfloat16 h = __float2bfloat16(f);   // RNE
    return *reinterpret_cast<unsigned short*>(&h);
}
__device__ __forceinline__ float b2f(unsigned short u) {
    union { unsigned int i; float f; } c; c.i = ((unsigned int)u) << 16; return c.f;
}

// (1/1.2)^e, compile-time folded under full unroll
__host__ __device__ constexpr float wpow(int e) {
    float r = 1.f;
    for (int i = 0; i < e; i++) r *= (1.0f / 1.2f);
    return r;
}

// Head-major address: hm[hd][tok][ch], ch in [0,32)
__device__ __forceinline__ size_t hm(int hd, int tok, int ch) {
    return (size_t)hd * ((size_t)NT * Dn) + (size_t)tok * Dn + ch;
}

// ---------------- K0: prep --------------------------------------------------
// blocks 0..255: relayout C f32 -> bf16 per-lane-contiguous image:
//   16B chunk g = ((hd*32 + i)*2 + half)*64 + lane,  lane=(kgrp<<4)|tloc
//   content    = C[hd][k=half*16+tloc][i][kgrp*8 .. +7]
// blocks 256..511: W[k][n] f32 -> Wt[n][k] bf16 (transpose).
__global__ __launch_bounds__(256) void prep_k(const float* __restrict__ C,
                                              unsigned short* __restrict__ Cl,
                                              const float* __restrict__ W,
                                              unsigned short* __restrict__ Wt) {
    __shared__ float tile[32][33];
    if (blockIdx.x < 256) {
        const int g = blockIdx.x * 256 + threadIdx.x;   // 65536 chunks
        const int hd = g >> 12, rem = g & 4095;
        const int i = rem >> 7, half = (rem >> 6) & 1, lane = rem & 63;
        const int tloc = lane & 15, kgrp = lane >> 4;
        const int k = half * 16 + tloc;
        const float* src = C + (size_t)hd * 32768 + (size_t)k * 1024 + i * 32 + kgrp * 8;
        float4 a = reinterpret_cast<const float4*>(src)[0];
        float4 b = reinterpret_cast<const float4*>(src)[1];
        u16x8 st;
        st[0]=f2b(a.x); st[1]=f2b(a.y); st[2]=f2b(a.z); st[3]=f2b(a.w);
        st[4]=f2b(b.x); st[5]=f2b(b.y); st[6]=f2b(b.z); st[7]=f2b(b.w);
        *reinterpret_cast<u16x8*>(Cl + (size_t)g * 8) = st;
    } else {
        const int bid = blockIdx.x - 256;
        const int kb = (bid & 15) * 32, nb = (bid >> 4) * 32;
        const int tx = threadIdx.x & 31, ty = threadIdx.x >> 5;   // ty 0..7
        #pragma unroll
        for (int j = 0; j < 4; j++)
            tile[ty + 8 * j][tx] = W[(size_t)(kb + ty + 8 * j) * En + nb + tx];
        __syncthreads();
        #pragma unroll
        for (int j = 0; j < 4; j++)
            Wt[(size_t)(nb + ty + 8 * j) * En + kb + tx] = f2b(tile[tx][ty + 8 * j]);
    }
}

// ---------------- K1: h = x @ W + b  (bf16 MFMA GEMM + fused local sums) -----
__global__ __launch_bounds__(256) void gemm_mfma_k(const float* __restrict__ x,
                                                   const unsigned short* __restrict__ Wt,
                                                   const float* __restrict__ bias,
                                                   unsigned short* __restrict__ h,
                                                   float* __restrict__ locals) {
    __shared__ unsigned short As[128][40];
    __shared__ unsigned short Bs[64][40];
    const int m0 = blockIdx.x * 128, n0 = blockIdx.y * 64;
    const int tid = threadIdx.x;
    const int wid = tid >> 6, lane = tid & 63;
    const int tloc = lane & 15, kgrp = lane >> 4;
    const int wr = wid >> 1, wc = wid & 1;

    const int ar = tid >> 1, ah = (tid & 1) * 16;
    const int brr = tid >> 2, bq = (tid & 3) * 8;

    f32x4 acc[4][2] = {};

    for (int k0 = 0; k0 < En; k0 += 32) {
        const float* xp = &x[(size_t)(m0 + ar) * En + k0 + ah];
        float4 a0 = reinterpret_cast<const float4*>(xp)[0];
        float4 a1 = reinterpret_cast<const float4*>(xp)[1];
        float4 a2 = reinterpret_cast<const float4*>(xp)[2];
        float4 a3 = reinterpret_cast<const float4*>(xp)[3];
        u16x8 bv = *reinterpret_cast<const u16x8*>(&Wt[(size_t)(n0 + brr) * En + k0 + bq]);
        __syncthreads();
        u16x8 w0, w1;
        w0[0]=f2b(a0.x); w0[1]=f2b(a0.y); w0[2]=f2b(a0.z); w0[3]=f2b(a0.w);
        w0[4]=f2b(a1.x); w0[5]=f2b(a1.y); w0[6]=f2b(a1.z); w0[7]=f2b(a1.w);
        w1[0]=f2b(a2.x); w1[1]=f2b(a2.y); w1[2]=f2b(a2.z); w1[3]=f2b(a2.w);
        w1[4]=f2b(a3.x); w1[5]=f2b(a3.y); w1[6]=f2b(a3.z); w1[7]=f2b(a3.w);
        *reinterpret_cast<u16x8*>(&As[ar][ah])     = w0;
        *reinterpret_cast<u16x8*>(&As[ar][ah + 8]) = w1;
        *reinterpret_cast<u16x8*>(&Bs[brr][bq])    = bv;
        __syncthreads();

        bf16x8 afr[4], bfr[2];
        #pragma unroll
        for (int m = 0; m < 4; m++)
            afr[m] = *reinterpret_cast<const bf16x8*>(&As[wr * 64 + m * 16 + tloc][kgrp * 8]);
        #pragma unroll
        for (int n = 0; n < 2; n++)
            bfr[n] = *reinterpret_cast<const bf16x8*>(&Bs[wc * 32 + n * 16 + tloc][kgrp * 8]);
        #pragma unroll
        for (int m = 0; m < 4; m++)
            #pragma unroll
            for (int n = 0; n < 2; n++)
                acc[m][n] = __builtin_amdgcn_mfma_f32_16x16x32_bf16(afr[m], bfr[n], acc[m][n], 0, 0, 0);
    }

    const float kmul = (kgrp & 1 ? 2.0736f : 1.f) * (kgrp & 2 ? 4.29981696f : 1.f);
    const int cg = blockIdx.x * 2 + wr;   // global 64-token chunk

    #pragma unroll
    for (int n = 0; n < 2; n++) {
        const int col = n0 + wc * 32 + n * 16 + tloc;
        const float bcol = bias[col];
        const int hd = col >> 5, ch = col & 31;
        float part = 0.f;
        #pragma unroll
        for (int m = 0; m < 4; m++)
            #pragma unroll
            for (int r = 0; r < 4; r++) {
                const int row = m0 + wr * 64 + m * 16 + kgrp * 4 + r;
                const unsigned short hb16 = f2b(acc[m][n][r] + bcol);
                h[hm(hd, row, ch)] = hb16;
                part += b2f(hb16) * (wpow(64 - m * 16 - r) * kmul);
            }
        part += __shfl_xor(part, 16);
        part += __shfl_xor(part, 32);
        if (kgrp == 0) locals[(size_t)cg * En + col] = part;
    }
}

// ---------------- K2: serial prefix over chunks ----------------
__global__ __launch_bounds__(512) void scan_prefix_k(const float* __restrict__ locals,
                                                     float* __restrict__ Acar) {
    const int b = blockIdx.x;
    const int e = threadIdx.x;
    float invRL = 1.f;
    #pragma unroll
    for (int i = 0; i < CL; i++) invRL *= INV_DECAY;
    float A = 0.f;
    for (int c = 0; c < NC; c++) {
        Acar[(size_t)(b * NC + c) * En + e] = A;
        A = A * invRL + locals[(size_t)(b * NC + c) * En + e];
    }
}

// ---------------- K3: bilinear v11 — pinned stationary C, 2 chunks/block ----
// Block: 256 thr = 4 waves, TWO 64-token chunks x 1 head.
// Wave w: i-slice [8w,8w+8); its 16 C-fragments loaded ONCE and pinned into
// VGPRs via inline-asm (defeats compiler load-sinking — the r11 diagnosis).
// Both KS scans done under one barrier pair; main loops are memory-free.
__global__ __launch_bounds__(256, 2) void bilinear11_k(const unsigned short* __restrict__ hg,
                                                       const float* __restrict__ Acar,
                                                       unsigned short* __restrict__ yb,
                                                       const unsigned short* __restrict__ Cl) {
    __shared__ unsigned short hs[2][64][40];   // 10 KB
    __shared__ unsigned short Ss[2][64][40];   // 10 KB
    __shared__ float ys[4][64][36];            // 36.9 KB -> 56.3 KB total, 2 blk/CU

    const int hd = blockIdx.y;
    const int cg0 = blockIdx.x * 2;            // first global chunk
    const int tokens0 = cg0 * 64;
    const int tid = threadIdx.x;
    const int wid = tid >> 6, lane = tid & 63;
    const int tloc = lane & 15, kgrp = lane >> 4;
    const int j0 = kgrp * 8;
    const int c0 = wid * 8;

    // ---- stationary A-frags: load once, PIN in VGPRs ----
    bf16x8 afr[8][2];
    {
        const unsigned short* cb = Cl + (size_t)hd * 32768;
        #pragma unroll
        for (int s = 0; s < 8; s++) {
            const int i = wid * 8 + s;
            #pragma unroll
            for (int mt = 0; mt < 2; mt++)
                afr[s][mt] = *reinterpret_cast<const bf16x8*>(
                    cb + ((size_t)((i * 2 + mt) * 64 + lane) * 8));
        }
    }
    #pragma unroll
    for (int s = 0; s < 8; s++)
        asm volatile("" : "+v"(afr[s][0]), "+v"(afr[s][1]));

    // ---- stage both h chunks (64 tok x 32 ch each) into LDS ----
    {
        const int tok = tid >> 2, c8 = (tid & 3) * 8;
        #pragma unroll
        for (int cc = 0; cc < 2; cc++)
            *reinterpret_cast<u16x8*>(&hs[cc][tok][c8]) =
                *reinterpret_cast<const u16x8*>(hg + hm(hd, tokens0 + cc * 64 + tok, c8));
    }
    __syncthreads();

    // ---- Kogge-Stone decayed prefix for BOTH chunks (lane = token) ----
    const float dt = exp2f((float)lane * LOG2_INVD);
    #pragma unroll
    for (int cc = 0; cc < 2; cc++) {
        float Ac[8];
        #pragma unroll
        for (int e = 0; e < 8; e++)
            Ac[e] = Acar[(size_t)(cg0 + cc) * En + hd * Dn + c0 + e];
        float P[8];
        u16x8 hv = *reinterpret_cast<const u16x8*>(&hs[cc][lane][c0]);
        #pragma unroll
        for (int e = 0; e < 8; e++) P[e] = b2f(hv[e]);
        #pragma unroll
        for (int k = 0; k < 6; k++) {
            const int dlt = 1 << k;
            const float wk = wpow(1 << k);
            #pragma unroll
            for (int e = 0; e < 8; e++) {
                float o = __shfl_up(P[e], dlt, 64);
                P[e] += (lane >= dlt) ? wk * o : 0.f;
            }
        }
        u16x8 sst;
        #pragma unroll
        for (int e = 0; e < 8; e++) {
            float pm1 = __shfl_up(P[e], 1, 64);
            if (lane == 0) pm1 = 0.f;
            sst[e] = f2b(Ac[e] * dt + INV_DECAY * pm1);
        }
        *reinterpret_cast<u16x8*>(&Ss[cc][lane][c0]) = sst;
    }
    __syncthreads();

    // ---- per-chunk: frags -> memory-free main loop -> LDS reduce -> store ----
    for (int cc = 0; cc < 2; cc++) {
        u16x8 hreg[4];
        float sf[4][8];
        #pragma unroll
        for (int nt = 0; nt < 4; nt++) {
            const int trow = nt * 16 + tloc;
            hreg[nt] = *reinterpret_cast<const u16x8*>(&hs[cc][trow][c0]);
            u16x8 sv = *reinterpret_cast<const u16x8*>(&Ss[cc][trow][j0]);
            #pragma unroll
            for (int e = 0; e < 8; e++) sf[nt][e] = b2f(sv[e]);
        }

        f32x4 acc[2][4] = {};
        #pragma unroll
        for (int s = 0; s < 8; s++) {
            #pragma unroll
            for (int nt = 0; nt < 4; nt++) {
                const float hsc = b2f(hreg[nt][s]);
                bf16x8 bfrag;
                #pragma unroll
                for (int e = 0; e < 8; e++) bfrag[e] = (short)f2b(hsc * sf[nt][e]);
                acc[0][nt] = __builtin_amdgcn_mfma_f32_16x16x32_bf16(afr[s][0], bfrag, acc[0][nt], 0, 0, 0);
                acc[1][nt] = __builtin_amdgcn_mfma_f32_16x16x32_bf16(afr[s][1], bfrag, acc[1][nt], 0, 0, 0);
            }
        }

        // partials to LDS (f32x4, 16B-aligned rows of 144B)
        #pragma unroll
        for (int mt = 0; mt < 2; mt++)
            #pragma unroll
            for (int nt = 0; nt < 4; nt++)
                *reinterpret_cast<f32x4*>(&ys[wid][nt * 16 + tloc][mt * 16 + kgrp * 4]) = acc[mt][nt];
        __syncthreads();

        // reduce 4 partials + residual, coalesced store
        {
            const int token = tid >> 2, q = tid & 3;
            f32x4 y0 = {0.f,0.f,0.f,0.f}, y1 = {0.f,0.f,0.f,0.f};
            #pragma unroll
            for (int w = 0; w < 4; w++) {
                const f32x4* src = reinterpret_cast<const f32x4*>(&ys[w][token][q * 8]);
                y0 += src[0];
                y1 += src[1];
            }
            u16x8 hres = *reinterpret_cast<const u16x8*>(&hs[cc][token][q * 8]);
            u16x8 st;
            #pragma unroll
            for (int e = 0; e < 4; e++) {
                st[e]     = f2b(y0[e] + b2f(hres[e]));
                st[4 + e] = f2b(y1[e] + b2f(hres[4 + e]));
            }
            *reinterpret_cast<u16x8*>(yb + hm(hd, tokens0 + cc * 64 + token, q * 8)) = st;
        }
        if (cc == 0) __syncthreads();   // protect ys before chunk 1 overwrites
    }
}

// ---------------- K4: LayerNorm over E=512 (head-major bf16 in, f32 out) ----
__global__ __launch_bounds__(256) void ln_k(const unsigned short* __restrict__ y,
                                            const float* __restrict__ gamma,
                                            const float* __restrict__ beta,
                                            float* __restrict__ out) {
    const int row = blockIdx.x * 4 + (threadIdx.x >> 6);
    const int lane = threadIdx.x & 63;
    u16x8 v = *reinterpret_cast<const u16x8*>(y + hm(lane >> 2, row, (lane & 3) * 8));
    float f[8];
    float s = 0.f, s2 = 0.f;
    #pragma unroll
    for (int e = 0; e < 8; e++) {
        f[e] = b2f(v[e]);
        s += f[e]; s2 += f[e] * f[e];
    }
    #pragma unroll
    for (int off = 1; off < 64; off <<= 1) {
        s  += __shfl_xor(s, off);
        s2 += __shfl_xor(s2, off);
    }
    const float mu = s * (1.f / En);
    const float var = s2 * (1.f / En) - mu * mu;
    const float rs = rsqrtf(var + 1e-3f);
    const int cbase = lane * 8;
    float4 g0 = reinterpret_cast<const float4*>(&gamma[cbase])[0];
    float4 g1 = reinterpret_cast<const float4*>(&gamma[cbase])[1];
    float4 b0 = reinterpret_cast<const float4*>(&beta[cbase])[0];
    float4 b1 = reinterpret_cast<const float4*>(&beta[cbase])[1];
    float4 o0, o1;
    o0.x = (f[0] - mu) * rs * g0.x + b0.x; o0.y = (f[1] - mu) * rs * g0.y + b0.y;
    o0.z = (f[2] - mu) * rs * g0.z + b0.z; o0.w = (f[3] - mu) * rs * g0.w + b0.w;
    o1.x = (f[4] - mu) * rs * g1.x + b1.x; o1.y = (f[5] - mu) * rs * g1.y + b1.y;
    o1.z = (f[6] - mu) * rs * g1.z + b1.z; o1.w = (f[7] - mu) * rs * g1.w + b1.w;
    float* op = out + (size_t)row * En;
    reinterpret_cast<float4*>(op)[lane * 2]     = o0;
    reinterpret_cast<float4*>(op)[lane * 2 + 1] = o1;
}

extern "C" void kernel_launch(void* const* d_in, const int* in_sizes, int n_in,
                              void* d_out, int out_size, void* d_ws, size_t ws_size,
                              hipStream_t stream) {
    const float* x     = (const float*)d_in[0];
    const float* W     = (const float*)d_in[1];
    const float* bias  = (const float*)d_in[2];
    const float* C     = (const float*)d_in[3];
    const float* gamma = (const float*)d_in[4];
    const float* beta  = (const float*)d_in[5];
    float* out = (float*)d_out;

    unsigned short* hb  = (unsigned short*)d_ws;             // head-major h
    unsigned short* yb  = hb + (size_t)Hn * NT * Dn;         // head-major y
    unsigned short* Cl  = yb + (size_t)Hn * NT * Dn;
    unsigned short* Wt  = Cl + (size_t)Hn * Dn * Dn * Dn;
    float* locals = (float*)(Wt + (size_t)En * En);
    float* Acar   = locals + (size_t)Bn * NC * En;

    prep_k<<<512, 256, 0, stream>>>(C, Cl, W, Wt);
    gemm_mfma_k<<<dim3(NT / 128, En / 64), 256, 0, stream>>>(x, Wt, bias, hb, locals);
    scan_prefix_k<<<Bn, 512, 0, stream>>>(locals, Acar);
    bilinear11_k<<<dim3(NT / 128, Hn), 256, 0, stream>>>(hb, Acar, yb, Cl);
    ln_k<<<NT / 4, 256, 0, stream>>>(yb, gamma, beta, out);
}

// Round 13
// 81.914 us; speedup vs baseline: 1.0669x; 1.0669x over previous
//
#include <hip/hip_runtime.h>
#include <hip/hip_bf16.h>

// Problem constants
#define Bn 8
#define Tn 2048
#define En 512
#define Hn 16
#define Dn 32
#define NC 32          // scan chunks
#define CL 64          // chunk length (Tn/NC)
#define NT (Bn*Tn)     // 16384 tokens
#define INV_DECAY (1.0f/1.2f)

typedef __attribute__((ext_vector_type(8))) short  bf16x8;  // 8 bf16 (4 VGPRs)
typedef __attribute__((ext_vector_type(4))) float  f32x4;
typedef __attribute__((ext_vector_type(8))) unsigned short u16x8;

__device__ __forceinline__ unsigned short f2b(float f) {
    __hip_bfloat16 h = __float2bfloat16(f);   // RNE
    return *reinterpret_cast<unsigned short*>(&h);
}
__device__ __forceinline__ float b2f(unsigned short u) {
    union { unsigned int i; float f; } c; c.i = ((unsigned int)u) << 16; return c.f;
}

// (1/1.2)^e, compile-time folded under full unroll
__host__ __device__ constexpr float wpow(int e) {
    float r = 1.f;
    for (int i = 0; i < e; i++) r *= (1.0f / 1.2f);
    return r;
}

// Head-major address: hm[hd][tok][ch], ch in [0,32)
__device__ __forceinline__ size_t hm(int hd, int tok, int ch) {
    return (size_t)hd * ((size_t)NT * Dn) + (size_t)tok * Dn + ch;
}

// ---------------- K0: prep --------------------------------------------------
// blocks 0..255: relayout C f32 -> bf16 per-lane-contiguous image:
//   16B chunk g = ((hd*32 + i)*2 + half)*64 + lane,  lane=(kgrp<<4)|tloc
//   content    = C[hd][k=half*16+tloc][i][kgrp*8 .. +7]
// blocks 256..511: W[k][n] f32 -> Wt[n][k] bf16 (transpose).
__global__ __launch_bounds__(256) void prep_k(const float* __restrict__ C,
                                              unsigned short* __restrict__ Cl,
                                              const float* __restrict__ W,
                                              unsigned short* __restrict__ Wt) {
    __shared__ float tile[32][33];
    if (blockIdx.x < 256) {
        const int g = blockIdx.x * 256 + threadIdx.x;   // 65536 chunks
        const int hd = g >> 12, rem = g & 4095;
        const int i = rem >> 7, half = (rem >> 6) & 1, lane = rem & 63;
        const int tloc = lane & 15, kgrp = lane >> 4;
        const int k = half * 16 + tloc;
        const float* src = C + (size_t)hd * 32768 + (size_t)k * 1024 + i * 32 + kgrp * 8;
        float4 a = reinterpret_cast<const float4*>(src)[0];
        float4 b = reinterpret_cast<const float4*>(src)[1];
        u16x8 st;
        st[0]=f2b(a.x); st[1]=f2b(a.y); st[2]=f2b(a.z); st[3]=f2b(a.w);
        st[4]=f2b(b.x); st[5]=f2b(b.y); st[6]=f2b(b.z); st[7]=f2b(b.w);
        *reinterpret_cast<u16x8*>(Cl + (size_t)g * 8) = st;
    } else {
        const int bid = blockIdx.x - 256;
        const int kb = (bid & 15) * 32, nb = (bid >> 4) * 32;
        const int tx = threadIdx.x & 31, ty = threadIdx.x >> 5;   // ty 0..7
        #pragma unroll
        for (int j = 0; j < 4; j++)
            tile[ty + 8 * j][tx] = W[(size_t)(kb + ty + 8 * j) * En + nb + tx];
        __syncthreads();
        #pragma unroll
        for (int j = 0; j < 4; j++)
            Wt[(size_t)(nb + ty + 8 * j) * En + kb + tx] = f2b(tile[tx][ty + 8 * j]);
    }
}

// ---------------- K1: h = x @ W + b  (bf16 MFMA GEMM + fused local sums) -----
__global__ __launch_bounds__(256) void gemm_mfma_k(const float* __restrict__ x,
                                                   const unsigned short* __restrict__ Wt,
                                                   const float* __restrict__ bias,
                                                   unsigned short* __restrict__ h,
                                                   float* __restrict__ locals) {
    __shared__ unsigned short As[128][40];
    __shared__ unsigned short Bs[64][40];
    const int m0 = blockIdx.x * 128, n0 = blockIdx.y * 64;
    const int tid = threadIdx.x;
    const int wid = tid >> 6, lane = tid & 63;
    const int tloc = lane & 15, kgrp = lane >> 4;
    const int wr = wid >> 1, wc = wid & 1;

    const int ar = tid >> 1, ah = (tid & 1) * 16;
    const int brr = tid >> 2, bq = (tid & 3) * 8;

    f32x4 acc[4][2] = {};

    for (int k0 = 0; k0 < En; k0 += 32) {
        const float* xp = &x[(size_t)(m0 + ar) * En + k0 + ah];
        float4 a0 = reinterpret_cast<const float4*>(xp)[0];
        float4 a1 = reinterpret_cast<const float4*>(xp)[1];
        float4 a2 = reinterpret_cast<const float4*>(xp)[2];
        float4 a3 = reinterpret_cast<const float4*>(xp)[3];
        u16x8 bv = *reinterpret_cast<const u16x8*>(&Wt[(size_t)(n0 + brr) * En + k0 + bq]);
        __syncthreads();
        u16x8 w0, w1;
        w0[0]=f2b(a0.x); w0[1]=f2b(a0.y); w0[2]=f2b(a0.z); w0[3]=f2b(a0.w);
        w0[4]=f2b(a1.x); w0[5]=f2b(a1.y); w0[6]=f2b(a1.z); w0[7]=f2b(a1.w);
        w1[0]=f2b(a2.x); w1[1]=f2b(a2.y); w1[2]=f2b(a2.z); w1[3]=f2b(a2.w);
        w1[4]=f2b(a3.x); w1[5]=f2b(a3.y); w1[6]=f2b(a3.z); w1[7]=f2b(a3.w);
        *reinterpret_cast<u16x8*>(&As[ar][ah])     = w0;
        *reinterpret_cast<u16x8*>(&As[ar][ah + 8]) = w1;
        *reinterpret_cast<u16x8*>(&Bs[brr][bq])    = bv;
        __syncthreads();

        bf16x8 afr[4], bfr[2];
        #pragma unroll
        for (int m = 0; m < 4; m++)
            afr[m] = *reinterpret_cast<const bf16x8*>(&As[wr * 64 + m * 16 + tloc][kgrp * 8]);
        #pragma unroll
        for (int n = 0; n < 2; n++)
            bfr[n] = *reinterpret_cast<const bf16x8*>(&Bs[wc * 32 + n * 16 + tloc][kgrp * 8]);
        #pragma unroll
        for (int m = 0; m < 4; m++)
            #pragma unroll
            for (int n = 0; n < 2; n++)
                acc[m][n] = __builtin_amdgcn_mfma_f32_16x16x32_bf16(afr[m], bfr[n], acc[m][n], 0, 0, 0);
    }

    const float kmul = (kgrp & 1 ? 2.0736f : 1.f) * (kgrp & 2 ? 4.29981696f : 1.f);
    const int cg = blockIdx.x * 2 + wr;   // global 64-token chunk

    #pragma unroll
    for (int n = 0; n < 2; n++) {
        const int col = n0 + wc * 32 + n * 16 + tloc;
        const float bcol = bias[col];
        const int hd = col >> 5, ch = col & 31;
        float part = 0.f;
        #pragma unroll
        for (int m = 0; m < 4; m++)
            #pragma unroll
            for (int r = 0; r < 4; r++) {
                const int row = m0 + wr * 64 + m * 16 + kgrp * 4 + r;
                const unsigned short hb16 = f2b(acc[m][n][r] + bcol);
                h[hm(hd, row, ch)] = hb16;
                part += b2f(hb16) * (wpow(64 - m * 16 - r) * kmul);
            }
        part += __shfl_xor(part, 16);
        part += __shfl_xor(part, 32);
        if (kgrp == 0) locals[(size_t)cg * En + col] = part;
    }
}

// ---------------- K2: serial prefix over chunks ----------------
__global__ __launch_bounds__(512) void scan_prefix_k(const float* __restrict__ locals,
                                                     float* __restrict__ Acar) {
    const int b = blockIdx.x;
    const int e = threadIdx.x;
    float invRL = 1.f;
    #pragma unroll
    for (int i = 0; i < CL; i++) invRL *= INV_DECAY;
    float A = 0.f;
    for (int c = 0; c < NC; c++) {
        Acar[(size_t)(b * NC + c) * En + e] = A;
        A = A * invRL + locals[(size_t)(b * NC + c) * En + e];
    }
}

// ---------------- K2c: emit S (bf16, head-major) ----------------------------
__global__ __launch_bounds__(512) void scan_emit_k(const unsigned short* __restrict__ h,
                                                   const float* __restrict__ Acar,
                                                   unsigned short* __restrict__ Sg) {
    const int c = blockIdx.x, b = blockIdx.y;
    const int e = threadIdx.x;
    const int hd = e >> 5, ch = e & 31;
    float s = Acar[(size_t)(b * NC + c) * En + e];
    const size_t base = hm(hd, b * Tn + c * CL, ch);
    for (int t = 0; t < CL; t++) {
        Sg[base + (size_t)t * Dn] = f2b(s);
        s = (s + b2f(h[base + (size_t)t * Dn])) * INV_DECAY;
    }
}

// ---------------- K3: bilinear v12 — lean v8 structure, higher occupancy ----
// Output y^T[k, tok]: A-operand = C2 slice (per-wave i in [8w,8w+8)),
// B-operand = h*S products (VALU). Block: 256 thr = 4 waves, 64 tokens, 1 head.
// No in-kernel scan, no h staging: h/S read straight from global (coalesced,
// L2-friendly). Partials reduced via LDS. launch_bounds(256,4) -> VGPR<=128,
// 4 blocks/CU x 4 waves = 16 waves/CU.
__global__ __launch_bounds__(256, 4) void bilinear12_k(const unsigned short* __restrict__ hg,
                                                       const unsigned short* __restrict__ Sg,
                                                       unsigned short* __restrict__ yb,
                                                       const unsigned short* __restrict__ Cl) {
    __shared__ float ys[4][64][36];   // 36.9 KB

    const int hd = blockIdx.y;
    const int tid = threadIdx.x;
    const int wid = tid >> 6, lane = tid & 63;
    const int tloc = lane & 15, kgrp = lane >> 4;
    const int j0 = kgrp * 8;
    const int tokens0 = blockIdx.x * 64;

    // ---- A-frags: C2[k_out=mt*16+tloc][i][j=kgrp*8+e], coalesced 16B/lane ----
    bf16x8 afr[8][2];
    {
        const unsigned short* cb = Cl + (size_t)hd * 32768;
        #pragma unroll
        for (int s = 0; s < 8; s++) {
            const int i = wid * 8 + s;
            #pragma unroll
            for (int mt = 0; mt < 2; mt++)
                afr[s][mt] = *reinterpret_cast<const bf16x8*>(
                    cb + ((size_t)((i * 2 + mt) * 64 + lane) * 8));
        }
    }

    // ---- h slice (this wave's 8 channels) + S fragments, per n-tile ----
    u16x8 hreg[4];
    float sf[4][8];
    #pragma unroll
    for (int nt = 0; nt < 4; nt++) {
        const int trow = tokens0 + nt * 16 + tloc;
        hreg[nt] = *reinterpret_cast<const u16x8*>(hg + hm(hd, trow, wid * 8));
        u16x8 sv = *reinterpret_cast<const u16x8*>(Sg + hm(hd, trow, j0));
        #pragma unroll
        for (int e = 0; e < 8; e++) sf[nt][e] = b2f(sv[e]);
    }

    // ---- main loop: 8 indep MFMA chains ----
    f32x4 acc[2][4] = {};
    #pragma unroll
    for (int s = 0; s < 8; s++) {
        #pragma unroll
        for (int nt = 0; nt < 4; nt++) {
            const float hsc = b2f(hreg[nt][s]);
            bf16x8 bfrag;
            #pragma unroll
            for (int e = 0; e < 8; e++) bfrag[e] = (short)f2b(hsc * sf[nt][e]);
            acc[0][nt] = __builtin_amdgcn_mfma_f32_16x16x32_bf16(afr[s][0], bfrag, acc[0][nt], 0, 0, 0);
            acc[1][nt] = __builtin_amdgcn_mfma_f32_16x16x32_bf16(afr[s][1], bfrag, acc[1][nt], 0, 0, 0);
        }
    }

    // ---- partials to LDS: acc[mt][nt][r] = y[k=mt*16+kgrp*4+r][tok=nt*16+tloc]
    #pragma unroll
    for (int mt = 0; mt < 2; mt++)
        #pragma unroll
        for (int nt = 0; nt < 4; nt++)
            *reinterpret_cast<f32x4*>(&ys[wid][nt * 16 + tloc][mt * 16 + kgrp * 4]) = acc[mt][nt];
    __syncthreads();

    // ---- reduce 4 partials + residual, coalesced store ----
    {
        const int token = tid >> 2, q = tid & 3;
        f32x4 y0 = {0.f,0.f,0.f,0.f}, y1 = {0.f,0.f,0.f,0.f};
        #pragma unroll
        for (int w = 0; w < 4; w++) {
            const f32x4* src = reinterpret_cast<const f32x4*>(&ys[w][token][q * 8]);
            y0 += src[0];
            y1 += src[1];
        }
        u16x8 hres = *reinterpret_cast<const u16x8*>(hg + hm(hd, tokens0 + token, q * 8));
        u16x8 st;
        #pragma unroll
        for (int e = 0; e < 4; e++) {
            st[e]     = f2b(y0[e] + b2f(hres[e]));
            st[4 + e] = f2b(y1[e] + b2f(hres[4 + e]));
        }
        *reinterpret_cast<u16x8*>(yb + hm(hd, tokens0 + token, q * 8)) = st;
    }
}

// ---------------- K4: LayerNorm over E=512 (head-major bf16 in, f32 out) ----
__global__ __launch_bounds__(256) void ln_k(const unsigned short* __restrict__ y,
                                            const float* __restrict__ gamma,
                                            const float* __restrict__ beta,
                                            float* __restrict__ out) {
    const int row = blockIdx.x * 4 + (threadIdx.x >> 6);
    const int lane = threadIdx.x & 63;
    u16x8 v = *reinterpret_cast<const u16x8*>(y + hm(lane >> 2, row, (lane & 3) * 8));
    float f[8];
    float s = 0.f, s2 = 0.f;
    #pragma unroll
    for (int e = 0; e < 8; e++) {
        f[e] = b2f(v[e]);
        s += f[e]; s2 += f[e] * f[e];
    }
    #pragma unroll
    for (int off = 1; off < 64; off <<= 1) {
        s  += __shfl_xor(s, off);
        s2 += __shfl_xor(s2, off);
    }
    const float mu = s * (1.f / En);
    const float var = s2 * (1.f / En) - mu * mu;
    const float rs = rsqrtf(var + 1e-3f);
    const int cbase = lane * 8;
    float4 g0 = reinterpret_cast<const float4*>(&gamma[cbase])[0];
    float4 g1 = reinterpret_cast<const float4*>(&gamma[cbase])[1];
    float4 b0 = reinterpret_cast<const float4*>(&beta[cbase])[0];
    float4 b1 = reinterpret_cast<const float4*>(&beta[cbase])[1];
    float4 o0, o1;
    o0.x = (f[0] - mu) * rs * g0.x + b0.x; o0.y = (f[1] - mu) * rs * g0.y + b0.y;
    o0.z = (f[2] - mu) * rs * g0.z + b0.z; o0.w = (f[3] - mu) * rs * g0.w + b0.w;
    o1.x = (f[4] - mu) * rs * g1.x + b1.x; o1.y = (f[5] - mu) * rs * g1.y + b1.y;
    o1.z = (f[6] - mu) * rs * g1.z + b1.z; o1.w = (f[7] - mu) * rs * g1.w + b1.w;
    float* op = out + (size_t)row * En;
    reinterpret_cast<float4*>(op)[lane * 2]     = o0;
    reinterpret_cast<float4*>(op)[lane * 2 + 1] = o1;
}

extern "C" void kernel_launch(void* const* d_in, const int* in_sizes, int n_in,
                              void* d_out, int out_size, void* d_ws, size_t ws_size,
                              hipStream_t stream) {
    const float* x     = (const float*)d_in[0];
    const float* W     = (const float*)d_in[1];
    const float* bias  = (const float*)d_in[2];
    const float* C     = (const float*)d_in[3];
    const float* gamma = (const float*)d_in[4];
    const float* beta  = (const float*)d_in[5];
    float* out = (float*)d_out;

    unsigned short* hb  = (unsigned short*)d_ws;             // head-major h
    unsigned short* Sg  = hb + (size_t)Hn * NT * Dn;         // head-major S, then y
    unsigned short* Cl  = Sg + (size_t)Hn * NT * Dn;
    unsigned short* Wt  = Cl + (size_t)Hn * Dn * Dn * Dn;
    float* locals = (float*)(Wt + (size_t)En * En);
    float* Acar   = locals + (size_t)Bn * NC * En;

    prep_k<<<512, 256, 0, stream>>>(C, Cl, W, Wt);
    gemm_mfma_k<<<dim3(NT / 128, En / 64), 256, 0, stream>>>(x, Wt, bias, hb, locals);
    scan_prefix_k<<<Bn, 512, 0, stream>>>(locals, Acar);
    scan_emit_k<<<dim3(NC, Bn), 512, 0, stream>>>(hb, Acar, Sg);
    bilinear12_k<<<dim3(NT / CL, Hn), 256, 0, stream>>>(hb, Sg, Sg /*y in-place over S*/, Cl);
    ln_k<<<NT / 4, 256, 0, stream>>>(Sg, gamma, beta, out);
}